// Round 5
// baseline (27693.747 us; speedup 1.0000x reference)
//
#include <hip/hip_runtime.h>
#include <stdint.h>

typedef __bf16 bf16;
typedef __attribute__((ext_vector_type(8))) __bf16 bf16x8;
typedef __attribute__((ext_vector_type(4))) float f32x4;

// ---------------- workspace layout (bytes), total ~45.1 MB ----------------
#define OFF_W0P   0ull
#define SZ_W0P    10485760ull
#define OFF_W1P   (OFF_W0P + SZ_W0P)
#define SZ_W1P    16777216ull
#define OFF_WOUT  (OFF_W1P + SZ_W1P)
#define SZ_WOUT   524288ull
#define OFF_B0P   (OFF_WOUT + SZ_WOUT)      // f32 permuted b0 [4096]
#define OFF_B1P   (OFF_B0P + 16384ull)      // f32 permuted b1 [4096]
#define OFF_BOP   (OFF_B1P + 16384ull)      // f32 bout [256]
#define OFF_BAR   (OFF_BOP + 1024ull)       // (legacy, unused)
#define OFF_FLAG  (OFF_BAR + 128ull)        // dtype flag: 1 = inputs are f32, 0 = bf16
#define OFF_H0PP  (OFF_BAR + 256ull)        // h0 ping-pong: 2 x 131072 (A-frag packed bf16)
#define OFF_H1PP  (OFF_H0PP + 262144ull)    // h1 ping-pong: 2 x 131072
#define OFF_XP    (OFF_H1PP + 262144ull)    // x repacked: [t 512][mt 4][kt 8][lane 64][8 bf16]
#define SZ_XP     16777216ull
#define OFF_FLAGS (OFF_XP + SZ_XP)          // barrier flags: uint[256], monotonic
// end = 45,123,840 bytes

#define OUT_FS0   8388608
#define OUT_FS1   8519680

// packed A-fragment byte offset for h buffers: element (batch b, unit u)
__device__ __forceinline__ size_t hpack_off(int b, int u) {
  return (size_t)((((b >> 4) * 32 + (u >> 5)) * 64 + ((b & 15) | (((u >> 3) & 3) << 4))) * 16 + ((u & 7) << 1));
}

__device__ __forceinline__ float sigm(float v) { return 1.0f / (1.0f + __expf(-v)); }
__device__ __forceinline__ float tanh_(float v) { return 2.0f / (1.0f + __expf(-2.0f * v)) - 1.0f; }
__device__ __forceinline__ float scrub(float v, float lim) { return fminf(fmaxf(v, -lim), lim); }

__device__ __forceinline__ float ldel(const void* p, size_t i, int fl) {
  return fl ? ((const float*)p)[i] : (float)((const bf16*)p)[i];
}

// ---------------- dtype detection ----------------
__global__ __launch_bounds__(256) void detect_kernel(const void* __restrict__ W0, char* __restrict__ ws) {
  __shared__ int cnt;
  if (threadIdx.x == 0) cnt = 0;
  __syncthreads();
  int local = 0;
  const unsigned* w = (const unsigned*)W0;
#pragma unroll
  for (int i = 0; i < 4; ++i) {
    unsigned e = (w[threadIdx.x * 4 + i] >> 7) & 0xFF;
    local += (e >= 0x68 && e <= 0x7E) ? 1 : 0;
  }
  atomicAdd(&cnt, local);
  __syncthreads();
  if (threadIdx.x == 0) *(unsigned*)(ws + OFF_FLAG) = (cnt < 512) ? 1u : 0u;
}

// ---------------- weight/x prep (unchanged from passing round) ----------------
__global__ __launch_bounds__(256) void prep_pack(const void* __restrict__ x, const void* __restrict__ W0,
                                                 const void* __restrict__ b0, const void* __restrict__ W1,
                                                 const void* __restrict__ b1, const void* __restrict__ Wout,
                                                 const void* __restrict__ bout, char* __restrict__ ws) {
  const int fl = *(const unsigned*)(ws + OFF_FLAG);
  int id = blockIdx.x * 256 + threadIdx.x;
  if (id < 5242880) {
    int tile = id / 20480, rem = id % 20480;
    int kt = rem >> 9, l = (rem >> 3) & 63, jj = rem & 7;
    int k = kt * 32 + ((l >> 4) << 3) + jj;
    int pc = tile * 16 + (l & 15);
    ((bf16*)(ws + OFF_W0P))[id] = (bf16)ldel(W0, (size_t)k * 4096 + (pc & 3) * 1024 + (pc >> 2), fl);
  } else if (id < 13631488) {
    int id2 = id - 5242880;
    int tile = id2 >> 15, rem = id2 & 32767;
    int kt = rem >> 9, l = (rem >> 3) & 63, jj = rem & 7;
    int k = kt * 32 + ((l >> 4) << 3) + jj;
    int pc = tile * 16 + (l & 15);
    ((bf16*)(ws + OFF_W1P))[id2] = (bf16)ldel(W1, (size_t)k * 4096 + (pc & 3) * 1024 + (pc >> 2), fl);
  } else if (id < 13893632) {
    int id2 = id - 13631488;
    int kt = id2 / 8192, rem = id2 % 8192;
    int nt = rem >> 9, l = (rem >> 3) & 63, jj = rem & 7;
    ((bf16*)(ws + OFF_WOUT))[id2] = (bf16)ldel(Wout, (size_t)(kt * 32 + ((l >> 4) << 3) + jj) * 256 + nt * 16 + (l & 15), fl);
  } else if (id < 13897728) {
    int pc = id - 13893632;
    ((float*)(ws + OFF_B0P))[pc] = ldel(b0, (pc & 3) * 1024 + (pc >> 2), fl);
  } else if (id < 13901824) {
    int pc = id - 13897728;
    ((float*)(ws + OFF_B1P))[pc] = ldel(b1, (pc & 3) * 1024 + (pc >> 2), fl);
  } else if (id < 13902080) {
    int pc = id - 13901824;
    ((float*)(ws + OFF_BOP))[pc] = ldel(bout, pc, fl);
  } else if (id < 22290688) {
    int id2 = id - 13902080;
    int t = id2 >> 14, rem = id2 & 16383;
    int mt = rem >> 12, rem2 = rem & 4095;
    int kt = rem2 >> 9, l = (rem2 >> 3) & 63, j = rem2 & 7;
    int b = mt * 16 + (l & 15);
    int v = kt * 32 + ((l >> 4) << 3) + j;
    ((bf16*)(ws + OFF_XP))[id2] = (bf16)ldel(x, ((size_t)b * 512 + t) * 256 + v, fl);
  }
}

// ---------------- initial h states + barrier flags ----------------
__global__ __launch_bounds__(256) void init_state(const void* __restrict__ s0, const void* __restrict__ s1,
                                                  char* __restrict__ ws) {
  const int fl = *(const unsigned*)(ws + OFF_FLAG);
  int id = blockIdx.x * 256 + threadIdx.x;
  if (id < 65536) {
    int b = id >> 10, u = id & 1023;
    *(bf16*)(ws + OFF_H0PP + 131072 + hpack_off(b, u)) = (bf16)ldel(s0, b * 2048 + 1024 + u, fl);
  } else if (id < 131072) {
    int id2 = id - 65536; int b = id2 >> 10, u = id2 & 1023;
    *(bf16*)(ws + OFF_H1PP + hpack_off(b, u)) = (bf16)ldel(s1, b * 2048 + 1024 + u, fl);
  } else if (id < 131328) {
    ((unsigned*)(ws + OFF_FLAGS))[id - 131072] = 0u;
  }
}

// ---------------- persistent kernel v2: k-split waves, B in registers, flag barrier ----------------
// 256 WGs x 256 threads. CU cu owns gate-col tiles cu of layer0/layer1; outproj job (nt,mo,dg).
// Wave w: B0 ktiles [10w,10w+10) (A kt same), B1 ktiles [16w,16w+16) (A kt 8+16w..),
// outproj: waves 2,3 own WOUT kt [0,16)/[16,32) (A kt 40..55 / 56..71, m=mo only).
// Per iter: direct global->VGPR A loads, MFMA into per-wave partials, LDS cross-wave reduce,
// wave w does pointwise for m-tile w. Barrier: release-store flags[cu]=it+1; relaxed spin; one acquire fence.
__global__ __launch_bounds__(256, 1) void recur_kernel(const void* __restrict__ s0, const void* __restrict__ s1,
                                                       char* __restrict__ ws, void* __restrict__ outv) {
  __shared__ __align__(16) char smem[36864];   // [0,16K) acc0 partials, [16K,32K) acc1, [32K,36K) accP
  const int fl = *(const unsigned*)(ws + OFF_FLAG);
  const int tid = threadIdx.x, lane = tid & 63, w = tid >> 6;
  const int cu = blockIdx.x;
  const int nt = cu & 15, mo = (cu >> 4) & 3, dg = cu >> 6;
  unsigned* flags = (unsigned*)(ws + OFF_FLAGS);

  auto store_out = [&](size_t idx, float v) {
    if (fl) ((float*)outv)[idx] = v; else ((bf16*)outv)[idx] = (bf16)v;
  };

  // ---- B fragments resident in registers ----
  bf16x8 b0reg[10], b1reg[16], wreg[16];
#pragma unroll
  for (int i = 0; i < 10; ++i)
    b0reg[i] = *(const bf16x8*)(ws + OFF_W0P + ((size_t)cu * 40 + w * 10 + i) * 1024 + (size_t)lane * 16);
#pragma unroll
  for (int i = 0; i < 16; ++i)
    b1reg[i] = *(const bf16x8*)(ws + OFF_W1P + ((size_t)cu * 64 + w * 16 + i) * 1024 + (size_t)lane * 16);
  if (w >= 2) {
#pragma unroll
    for (int i = 0; i < 16; ++i)
      wreg[i] = *(const bf16x8*)(ws + OFF_WOUT + ((size_t)(((w - 2) * 16 + i) * 16 + nt) * 64 + lane) * 16);
  }

  const float bini0 = ((const float*)(ws + OFF_B0P))[cu * 16 + (lane & 15)];
  const float bini1 = ((const float*)(ws + OFF_B1P))[cu * 16 + (lane & 15)];
  const float boN = ((const float*)(ws + OFF_BOP))[nt * 16 + (lane & 15)];
  const int u0 = cu * 4 + ((lane & 15) >> 2);
  float c0reg[4], c1reg[4];
#pragma unroll
  for (int r = 0; r < 4; ++r) {
    int b = w * 16 + ((lane >> 4) << 2) + r;   // wave w owns m-tile w for pointwise/state
    c0reg[r] = ldel(s0, b * 2048 + u0, fl);
    c1reg[r] = ldel(s1, b * 2048 + u0, fl);
  }

  for (int it = 0; it < 514; ++it) {
    const bool a0 = (it < 512);
    const bool a1 = (it >= 1 && it <= 512);
    const bool aP = (it >= 2 && ((it - 2) & 3) == dg);
    const char* h0src = ws + OFF_H0PP + (size_t)((it + 1) & 1) * 131072;   // h0(it-1)
    const char* h1src = ws + OFF_H1PP + (size_t)((it + 1) & 1) * 131072;   // h1(it-2)
    const char* xsrc  = ws + OFF_XP + (size_t)it * 32768;

    // ---- barrier wait: all CUs completed iter it-1 ----
    if (it >= 1) {
      unsigned tgt = (unsigned)it;
      bool ready;
      do {
        int ok = 1;
#pragma unroll
        for (int i = 0; i < 4; ++i) {
          unsigned v = __hip_atomic_load(&flags[lane * 4 + i], __ATOMIC_RELAXED, __HIP_MEMORY_SCOPE_AGENT);
          ok &= (v >= tgt) ? 1 : 0;
        }
        ready = __all(ok);
        if (!ready) __builtin_amdgcn_s_sleep(1);
      } while (!ready);
      __builtin_amdgcn_fence(__ATOMIC_ACQUIRE, "agent");   // one L2-inv per wave per iter
    }

    f32x4 acc0[4], acc1[4], accP;
#pragma unroll
    for (int m = 0; m < 4; ++m) {
#pragma unroll
      for (int r = 0; r < 4; ++r) { acc0[m][r] = bini0; acc1[m][r] = bini1; }
    }
#pragma unroll
    for (int r = 0; r < 4; ++r) accP[r] = 0.f;

    // ---- phase 1: gates0, A kt = 10w+i (x for kt<8, else h0) ----
    if (a0) {
#pragma unroll
      for (int h = 0; h < 2; ++h) {
        bf16x8 a1b[5][4];
#pragma unroll
        for (int i = 0; i < 5; ++i) {
          int kt = w * 10 + h * 5 + i;
#pragma unroll
          for (int m = 0; m < 4; ++m) {
            const char* src = (kt < 8) ? xsrc + (size_t)((m * 8 + kt) * 64 + lane) * 16
                                       : h0src + (size_t)((m * 32 + (kt - 8)) * 64 + lane) * 16;
            a1b[i][m] = *(const bf16x8*)src;
          }
        }
#pragma unroll
        for (int i = 0; i < 5; ++i) {
#pragma unroll
          for (int m = 0; m < 4; ++m)
            acc0[m] = __builtin_amdgcn_mfma_f32_16x16x32_bf16(a1b[i][m], b0reg[h * 5 + i], acc0[m], 0, 0, 0);
        }
      }
    }

    // ---- phase 2: gates1 (+ fused outproj), A kt = 8+16w+i (h0 for kt<40, else h1) ----
    if (a1 || (aP && w >= 2)) {
#pragma unroll
      for (int h = 0; h < 2; ++h) {
        bf16x8 a2b[8][4];
#pragma unroll
        for (int i = 0; i < 8; ++i) {
          int kt = 8 + w * 16 + h * 8 + i;
#pragma unroll
          for (int m = 0; m < 4; ++m) {
            const char* src = (kt < 40) ? h0src + (size_t)((m * 32 + (kt - 8)) * 64 + lane) * 16
                                        : h1src + (size_t)((m * 32 + (kt - 40)) * 64 + lane) * 16;
            a2b[i][m] = *(const bf16x8*)src;
          }
        }
#pragma unroll
        for (int i = 0; i < 8; ++i) {
          int i2 = h * 8 + i;
          if (a1) {
#pragma unroll
            for (int m = 0; m < 4; ++m)
              acc1[m] = __builtin_amdgcn_mfma_f32_16x16x32_bf16(a2b[i][m], b1reg[i2], acc1[m], 0, 0, 0);
          }
          if (aP && w >= 2)
            accP = __builtin_amdgcn_mfma_f32_16x16x32_bf16(a2b[i][mo], wreg[i2], accP, 0, 0, 0);
        }
      }
    }

    // ---- cross-wave reduction through LDS ----
#pragma unroll
    for (int m = 0; m < 4; ++m) {
      *(f32x4*)(smem + (size_t)(((w * 4 + m) * 64 + lane)) * 16) = acc0[m];
      *(f32x4*)(smem + 16384 + (size_t)(((w * 4 + m) * 64 + lane)) * 16) = acc1[m];
    }
    if (aP && w >= 2) *(f32x4*)(smem + 32768 + (size_t)(w * 64 + lane) * 16) = accP;
    __syncthreads();

    f32x4 g0, g1;
    {
      g0 = *(const f32x4*)(smem + (size_t)((0 * 4 + w) * 64 + lane) * 16);
      g1 = *(const f32x4*)(smem + 16384 + (size_t)((0 * 4 + w) * 64 + lane) * 16);
#pragma unroll
      for (int w2 = 1; w2 < 4; ++w2) {
        f32x4 p0 = *(const f32x4*)(smem + (size_t)((w2 * 4 + w) * 64 + lane) * 16);
        f32x4 p1 = *(const f32x4*)(smem + 16384 + (size_t)((w2 * 4 + w) * 64 + lane) * 16);
#pragma unroll
        for (int r = 0; r < 4; ++r) { g0[r] += p0[r]; g1[r] += p1[r]; }
      }
    }

    // ---- pointwise: wave w handles m-tile w; quad lanes hold gates i,j,f,o of unit u0 ----
    const int base = lane & 60;
    if (a0) {
      char* h0w = ws + OFF_H0PP + (size_t)(it & 1) * 131072;
#pragma unroll
      for (int r = 0; r < 4; ++r) {
        float z = g0[r];
        float zi = scrub(__shfl(z, base + 0, 64), 80.f);
        float zj = scrub(__shfl(z, base + 1, 64), 80.f);
        float zf = scrub(__shfl(z, base + 2, 64), 80.f);
        float zo = scrub(__shfl(z, base + 3, 64), 80.f);
        float c = c0reg[r];
        c = c * sigm(zf + 1.0f) + sigm(zi) * tanh_(zj);
        c = scrub(c, 1000.f);
        float hh = tanh_(c) * sigm(zo);
        c0reg[r] = c;
        if ((lane & 3) == 0) {
          int b = w * 16 + ((lane >> 4) << 2) + r;
          *(bf16*)(h0w + hpack_off(b, u0)) = (bf16)hh;
          if (it == 511) { store_out(OUT_FS0 + b * 2048 + u0, c); store_out(OUT_FS0 + b * 2048 + 1024 + u0, hh); }
        }
      }
    }
    if (a1) {
      char* h1w = ws + OFF_H1PP + (size_t)(it & 1) * 131072;
#pragma unroll
      for (int r = 0; r < 4; ++r) {
        float z = g1[r];
        float zi = scrub(__shfl(z, base + 0, 64), 80.f);
        float zj = scrub(__shfl(z, base + 1, 64), 80.f);
        float zf = scrub(__shfl(z, base + 2, 64), 80.f);
        float zo = scrub(__shfl(z, base + 3, 64), 80.f);
        float c = c1reg[r];
        c = c * sigm(zf + 1.0f) + sigm(zi) * tanh_(zj);
        c = scrub(c, 1000.f);
        float hh = tanh_(c) * sigm(zo);
        c1reg[r] = c;
        if ((lane & 3) == 0) {
          int b = w * 16 + ((lane >> 4) << 2) + r;
          *(bf16*)(h1w + hpack_off(b, u0)) = (bf16)hh;
          if (it == 512) { store_out(OUT_FS1 + b * 2048 + u0, c); store_out(OUT_FS1 + b * 2048 + 1024 + u0, hh); }
        }
      }
    }
    if (aP && w == mo) {   // outproj epilogue: sum wave-2/3 partials, write out[:, it-2, nt-tile]
      f32x4 s2 = *(const f32x4*)(smem + 32768 + (size_t)(2 * 64 + lane) * 16);
      f32x4 s3 = *(const f32x4*)(smem + 32768 + (size_t)(3 * 64 + lane) * 16);
      int t = it - 2;
#pragma unroll
      for (int r = 0; r < 4; ++r) {
        int b = mo * 16 + ((lane >> 4) << 2) + r;
        store_out(((size_t)b * 512 + t) * 256 + nt * 16 + (lane & 15), s2[r] + s3[r] + boN);
      }
    }

    // ---- barrier arrive: all waves' stores drained, then release flag ----
    __syncthreads();
    if (tid == 0) {
      __builtin_amdgcn_fence(__ATOMIC_RELEASE, "agent");   // writeback dirty L2 (h/out stores)
      __hip_atomic_store(&flags[cu], (unsigned)(it + 1), __ATOMIC_RELAXED, __HIP_MEMORY_SCOPE_AGENT);
    }
  }
}

extern "C" void kernel_launch(void* const* d_in, const int* in_sizes, int n_in,
                              void* d_out, int out_size, void* d_ws, size_t ws_size,
                              hipStream_t stream) {
  const void* x    = d_in[0];
  const void* s0   = d_in[1];
  const void* s1   = d_in[2];
  const void* W0   = d_in[3];
  const void* b0   = d_in[4];
  const void* W1   = d_in[5];
  const void* b1   = d_in[6];
  const void* Wout = d_in[7];
  const void* bout = d_in[8];
  char* ws = (char*)d_ws;
  (void)in_sizes; (void)n_in; (void)out_size; (void)ws_size;

  hipLaunchKernelGGL(detect_kernel, dim3(1),     dim3(256), 0, stream, W0, ws);
  hipLaunchKernelGGL(prep_pack,     dim3(87073), dim3(256), 0, stream, x, W0, b0, W1, b1, Wout, bout, ws);
  hipLaunchKernelGGL(init_state,    dim3(513),   dim3(256), 0, stream, s0, s1, ws);
  hipLaunchKernelGGL(recur_kernel,  dim3(256),   dim3(256), 0, stream, s0, s1, ws, d_out);
}